// Round 7
// baseline (1290.085 us; speedup 1.0000x reference)
//
#include <hip/hip_runtime.h>
#include <math.h>

constexpr int Bb = 4, Nn = 2048, Dd = 2048, Ee = 8, Cbn = 512;
constexpr int Mm = Bb * Nn;  // 8192 tokens
constexpr int NBLK = 512;    // persistent blocks: 2/CU (capacity is 4/CU)

typedef _Float16 half8 __attribute__((ext_vector_type(8)));
typedef float floatx16 __attribute__((ext_vector_type(16)));

#define GLL16(g, l)                                                     \
  __builtin_amdgcn_global_load_lds(                                     \
      (const __attribute__((address_space(1))) void*)(g),               \
      (__attribute__((address_space(3))) void*)(l), 16, 0, 0)

// Device-scope sense-free grid barrier: one monotone counter per stage,
// zeroed by hipMemsetAsync before launch. All 512 blocks are co-resident
// (2/CU needed vs 4/CU capacity at 32KB LDS, <=128 VGPR), so the spin is
// deadlock-free; __threadfence provides device-scope release of prior
// global writes, the acquire load pairs with it.
__device__ inline void grid_barrier(int* cnt) {
  __syncthreads();
  if (threadIdx.x == 0) {
    __threadfence();
    atomicAdd(cnt, 1);
    while (__hip_atomic_load(cnt, __ATOMIC_ACQUIRE, __HIP_MEMORY_SCOPE_AGENT) <
           NBLK) {
    }
  }
  __syncthreads();
}

__global__ __launch_bounds__(256, 2) void mega(
    const float* __restrict__ X, const float* __restrict__ W,
    _Float16* __restrict__ WThi, _Float16* __restrict__ WTlo,
    float* __restrict__ partial, int* __restrict__ ig,
    float* __restrict__ p1g, float* __restrict__ p2g, int* __restrict__ prios,
    int* __restrict__ bar, float* __restrict__ out, int cap) {
  __shared__ __align__(16) char smem[32768];
  const int tid = threadIdx.x;

  // ================= Phase A: transpose + split W ==========================
  {
    _Float16(*thi)[72] = (_Float16(*)[72])smem;            // 9216 B
    _Float16(*tlo)[72] = (_Float16(*)[72])(smem + 9216);   // 9216 B
    const int tx = tid & 15, ty = tid >> 4;
    for (int i = 0; i < 4; ++i) {
      __syncthreads();  // LDS reuse across tiles
      const int T = blockIdx.x * 4 + i;  // 0..2047
      const int kt = T & 31, ct = (T >> 5) & 7, e = T >> 8;
      const float* src = W + ((size_t)(e * 2048 + kt * 64)) * 512 + ct * 64;
#pragma unroll
      for (int p = 0; p < 4; ++p) {
        int kk = ty + p * 16;
        float4 v = *(const float4*)(src + (size_t)kk * 512 + tx * 4);
        _Float16 h;
        h = (_Float16)v.x; thi[tx * 4 + 0][kk] = h; tlo[tx * 4 + 0][kk] = (_Float16)(v.x - (float)h);
        h = (_Float16)v.y; thi[tx * 4 + 1][kk] = h; tlo[tx * 4 + 1][kk] = (_Float16)(v.y - (float)h);
        h = (_Float16)v.z; thi[tx * 4 + 2][kk] = h; tlo[tx * 4 + 2][kk] = (_Float16)(v.z - (float)h);
        h = (_Float16)v.w; thi[tx * 4 + 3][kk] = h; tlo[tx * 4 + 3][kk] = (_Float16)(v.w - (float)h);
      }
      __syncthreads();
      const int rr = tid >> 3;  // 0..31
      const int ch = tid & 7;   // 16B chunk
      _Float16* dh = WThi + ((size_t)(e * 512 + ct * 64)) * 2048 + kt * 64;
      _Float16* dl = WTlo + ((size_t)(e * 512 + ct * 64)) * 2048 + kt * 64;
#pragma unroll
      for (int p = 0; p < 2; ++p) {
        int cc = rr + p * 32;
        *(half8*)(dh + (size_t)cc * 2048 + ch * 8) = *(const half8*)(&thi[cc][ch * 8]);
        *(half8*)(dl + (size_t)cc * 2048 + ch * 8) = *(const half8*)(&tlo[cc][ch * 8]);
      }
    }
  }
  grid_barrier(bar + 0);

  // ================= Phase B: MFMA GEMM + square-reduce ====================
  {
    char* ldsA = smem;            // 128 rows x 128B fp32, 8-chunk XOR swizzle
    char* ldsBhi = smem + 16384;  // 128 rows x 64B fp16, 4-chunk XOR swizzle
    char* ldsBlo = smem + 24576;

    const int wave = tid >> 6, lane = tid & 63;
    const int wm = wave >> 1, wn = wave & 1;
    const int h = lane >> 5;

    // tile-independent lane addressing
    const int lrA = lane >> 3;
    const int cposA = lane & 7;
    const int cgA = cposA ^ lrA;
    int ldsAoff[4];
#pragma unroll
    for (int q = 0; q < 4; ++q) ldsAoff[q] = (wave * 32 + q * 8) * 128;

    const int lrB = lane >> 2;
    const int cposB = lane & 3;
    const int cgB = cposB ^ ((lrB >> 1) & 3);
    const int lqB0 = wave * 2048;
    const int lqB1 = lqB0 + 1024;

    const int keyA = lane & 7;
    const int rowA0 = wm * 64 + (lane & 31);
    const int rowA1 = rowA0 + 32;
    int oAf0[2][2], oAf1[2][2];
#pragma unroll
    for (int s = 0; s < 2; ++s)
#pragma unroll
      for (int c = 0; c < 2; ++c) {
        const int g = s * 4 + h * 2 + c;
        oAf0[s][c] = rowA0 * 128 + ((g ^ keyA) << 4);
        oAf1[s][c] = rowA1 * 128 + ((g ^ keyA) << 4);
      }

    const int rB0 = wn * 64 + (lane & 31);
    const int rB1 = rB0 + 32;
    auto foffB = [&](int r, int s) {
      return r * 64 + (((s * 2 + h) ^ ((r >> 1) & 3)) << 4);
    };
    const int oB0[2] = {foffB(rB0, 0), foffB(rB0, 1)};
    const int oB1[2] = {foffB(rB1, 0), foffB(rB1, 1)};

    auto cvtA = [](const char* p0, const char* p1, half8& ah, half8& al) {
      float4 f0 = *(const float4*)p0;
      float4 f1 = *(const float4*)p1;
      float xf[8] = {f0.x, f0.y, f0.z, f0.w, f1.x, f1.y, f1.z, f1.w};
#pragma unroll
      for (int j = 0; j < 8; ++j) {
        _Float16 hv = (_Float16)xf[j];
        ah[j] = hv;
        al[j] = (_Float16)(xf[j] - (float)hv);
      }
    };

    for (int j = 0; j < 4; ++j) {
      const int bid = blockIdx.x * 4 + j;  // 0..2047
      const int st = bid >> 8;
      const int stm = st & 3;
      const int stn = st >> 2;
      const int li = bid & 255;
      const int mtile = stm * 16 + (li >> 4);
      const int ntile = stn * 16 + (li & 15);

      const float* xg[4];
#pragma unroll
      for (int q = 0; q < 4; ++q) {
        const int row = wave * 32 + q * 8 + lrA;
        xg[q] = X + (size_t)(mtile * 128 + row) * 2048 + cgA * 4;
      }
      const int rB0s = wave * 32 + lrB;
      const int rB1s = rB0s + 16;
      const _Float16* wh0 = WThi + (size_t)(ntile * 128 + rB0s) * 2048 + cgB * 8;
      const _Float16* wh1 = WThi + (size_t)(ntile * 128 + rB1s) * 2048 + cgB * 8;
      const _Float16* wl0 = WTlo + (size_t)(ntile * 128 + rB0s) * 2048 + cgB * 8;
      const _Float16* wl1 = WTlo + (size_t)(ntile * 128 + rB1s) * 2048 + cgB * 8;

      floatx16 acc00 = {}, acc01 = {}, acc10 = {}, acc11 = {};

      __syncthreads();  // LDS reuse across tiles / phase A
      for (int kt = 0; kt < 64; ++kt) {
        const int k0 = kt * 32;
#pragma unroll
        for (int q = 0; q < 4; ++q) GLL16(xg[q] + k0, ldsA + ldsAoff[q]);
        GLL16(wh0 + k0, ldsBhi + lqB0);
        GLL16(wh1 + k0, ldsBhi + lqB1);
        GLL16(wl0 + k0, ldsBlo + lqB0);
        GLL16(wl1 + k0, ldsBlo + lqB1);
        __syncthreads();
#pragma unroll
        for (int s = 0; s < 2; ++s) {
          half8 ah0, al0, ah1, al1;
          cvtA(ldsA + oAf0[s][0], ldsA + oAf0[s][1], ah0, al0);
          cvtA(ldsA + oAf1[s][0], ldsA + oAf1[s][1], ah1, al1);
          half8 bh0 = *(const half8*)(ldsBhi + oB0[s]);
          half8 bh1 = *(const half8*)(ldsBhi + oB1[s]);
          half8 bl0 = *(const half8*)(ldsBlo + oB0[s]);
          half8 bl1 = *(const half8*)(ldsBlo + oB1[s]);
          acc00 = __builtin_amdgcn_mfma_f32_32x32x16_f16(ah0, bh0, acc00, 0, 0, 0);
          acc00 = __builtin_amdgcn_mfma_f32_32x32x16_f16(ah0, bl0, acc00, 0, 0, 0);
          acc00 = __builtin_amdgcn_mfma_f32_32x32x16_f16(al0, bh0, acc00, 0, 0, 0);
          acc01 = __builtin_amdgcn_mfma_f32_32x32x16_f16(ah0, bh1, acc01, 0, 0, 0);
          acc01 = __builtin_amdgcn_mfma_f32_32x32x16_f16(ah0, bl1, acc01, 0, 0, 0);
          acc01 = __builtin_amdgcn_mfma_f32_32x32x16_f16(al0, bh1, acc01, 0, 0, 0);
          acc10 = __builtin_amdgcn_mfma_f32_32x32x16_f16(ah1, bh0, acc10, 0, 0, 0);
          acc10 = __builtin_amdgcn_mfma_f32_32x32x16_f16(ah1, bl0, acc10, 0, 0, 0);
          acc10 = __builtin_amdgcn_mfma_f32_32x32x16_f16(al1, bh0, acc10, 0, 0, 0);
          acc11 = __builtin_amdgcn_mfma_f32_32x32x16_f16(ah1, bh1, acc11, 0, 0, 0);
          acc11 = __builtin_amdgcn_mfma_f32_32x32x16_f16(ah1, bl1, acc11, 0, 0, 0);
          acc11 = __builtin_amdgcn_mfma_f32_32x32x16_f16(al1, bh1, acc11, 0, 0, 0);
        }
        __syncthreads();
      }

      float myv = 0.f;
#pragma unroll
      for (int i = 0; i < 2; ++i) {
        const floatx16& c0 = i ? acc10 : acc00;
        const floatx16& c1 = i ? acc11 : acc01;
#pragma unroll
        for (int reg = 0; reg < 16; ++reg) {
          float v = c0[reg] * c0[reg] + c1[reg] * c1[reg];
#pragma unroll
          for (int m = 1; m <= 16; m <<= 1) v += __shfl_xor(v, m, 64);
          if ((lane & 31) == i * 16 + reg) myv = v;
        }
      }
      {
        const int i = (lane & 31) >> 4;
        const int reg = lane & 15;
        const int row = i * 32 + (reg & 3) + 8 * (reg >> 2) + 4 * h;
        const int token = mtile * 128 + wm * 64 + row;
        const int slice = ntile * 2 + wn;  // e*8+u
        partial[(size_t)token * 64 + slice] = myv;
      }
    }
  }
  grid_barrier(bar + 1);

  // ================= Phase C: softmax + top2 + capacity scan ===============
  if (blockIdx.x < Bb) {
    const int b = blockIdx.x;
    unsigned char* sI1 = (unsigned char*)smem;          // 2048
    unsigned char* sI2 = (unsigned char*)(smem + 2048); // 2048
    int(*cnts)[8] = (int(*)[8])(smem + 4096);           // 8192
    for (int i = 0; i < 8; ++i) {
      const int tl = i * 256 + tid;
      const int t = b * Nn + tl;
      float l[Ee];
      float mx = -1e30f;
#pragma unroll
      for (int e = 0; e < Ee; ++e) {
        float s = 0.f;
#pragma unroll
        for (int u = 0; u < 8; ++u) s += partial[(size_t)t * 64 + e * 8 + u];
        l[e] = sqrtf(s);
        mx = fmaxf(mx, l[e]);
      }
      float sum = 0.f, pe[Ee];
#pragma unroll
      for (int e = 0; e < Ee; ++e) {
        pe[e] = expf(l[e] - mx);
        sum += pe[e];
      }
      float inv = 1.f / sum;
      int i1 = 0;
      float b1 = l[0];
#pragma unroll
      for (int e = 1; e < Ee; ++e)
        if (l[e] > b1) { b1 = l[e]; i1 = e; }
      int i2 = -1;
      float b2 = -1e30f;
#pragma unroll
      for (int e = 0; e < Ee; ++e)
        if (e != i1 && l[e] > b2) { b2 = l[e]; i2 = e; }
      sI1[tl] = (unsigned char)i1;
      sI2[tl] = (unsigned char)i2;
      ig[t] = i1 | (i2 << 8);
      p1g[t] = pe[i1] * inv;
      p2g[t] = pe[i2] * inv;
    }
    __syncthreads();
    int cnt[8] = {0, 0, 0, 0, 0, 0, 0, 0};
    int eloc[16];
    const int base_p = tid * 16;
#pragma unroll
    for (int i = 0; i < 16; ++i) {
      int pp = base_p + i;
      int k = pp >> 11;
      int n = pp & (Nn - 1);
      int e = k == 0 ? (int)sI1[n] : (int)sI2[n];
      eloc[i] = e;
      cnt[e]++;
    }
#pragma unroll
    for (int e = 0; e < 8; ++e) cnts[tid][e] = cnt[e];
    __syncthreads();
    if (tid < 8) {
      int run = 0;
      for (int i = 0; i < 256; ++i) {
        int v = cnts[i][tid];
        cnts[i][tid] = run;
        run += v;
      }
    }
    __syncthreads();
    int base[8];
#pragma unroll
    for (int e = 0; e < 8; ++e) base[e] = cnts[tid][e];
#pragma unroll
    for (int i = 0; i < 16; ++i) {
      int e = eloc[i];
      prios[b * 2 * Nn + base_p + i] = base[e]++;
    }
  }
  grid_barrier(bar + 2);

  // ================= Phase D: fused zero + scatter =========================
  {
    const int row4 = Ee * 640 / 4;  // 1280 float4 per row (cap=640)
    for (int i = 0; i < 16; ++i) {
      const int t = blockIdx.x * 16 + i;
      const int b = t >> 11, n = t & (Nn - 1);
      const int pair = ig[t];
      const int e1 = pair & 0xff, e2 = (pair >> 8) & 0xff;
      const int q1 = prios[b * 2 * Nn + n];
      const int q2 = prios[b * 2 * Nn + Nn + n];
      const float v1 = p1g[t], v2 = p2g[t];
      const int g1 = (q1 < cap) ? e1 * cap + q1 : -1;
      const int g2 = (q2 < cap) ? e2 * cap + q2 : -1;
      float4* drow = (float4*)out + (size_t)t * (Ee * cap / 4);
      float4* crow = drow + (size_t)Mm * (Ee * cap / 4);
      for (int f = tid; f < Ee * cap / 4; f += 256) {
        float4 d = make_float4(0.f, 0.f, 0.f, 0.f);
        float4 c = make_float4(0.f, 0.f, 0.f, 0.f);
        const int base = f * 4;
        if (g1 >= base && g1 < base + 4) {
          ((float*)&d)[g1 - base] = 1.f;
          ((float*)&c)[g1 - base] = v1;
        }
        if (g2 >= base && g2 < base + 4) {
          ((float*)&d)[g2 - base] = 1.f;
          ((float*)&c)[g2 - base] = v2;
        }
        drow[f] = d;
        crow[f] = c;
      }
    }
    (void)row4;
  }
}

extern "C" void kernel_launch(void* const* d_in, const int* in_sizes, int n_in,
                              void* d_out, int out_size, void* d_ws, size_t ws_size,
                              hipStream_t stream) {
  const float* X = (const float*)d_in[0];
  const float* W = (const float*)d_in[1];
  float* out = (float*)d_out;
  const int cap = out_size / (2 * Bb * Nn * Ee);  // 640

  char* ws = (char*)d_ws;
  _Float16* WThi = (_Float16*)ws;                    // 16 MB
  _Float16* WTlo = (_Float16*)(ws + 16777216ull);    // 16 MB
  float* partial = (float*)(ws + 33554432ull);       // 2 MB
  int* ig = (int*)(ws + 35651584ull);                // 32 KB
  float* p1g = (float*)(ws + 35684352ull);           // 32 KB
  float* p2g = (float*)(ws + 35717120ull);           // 32 KB
  int* prios = (int*)(ws + 35749888ull);             // 64 KB
  int* bar = (int*)(ws + 35815424ull);               // barrier counters

  hipMemsetAsync(bar, 0, 256, stream);  // capture-safe, every call
  mega<<<NBLK, 256, 0, stream>>>(X, W, WThi, WTlo, partial, ig, p1g, p2g,
                                 prios, bar, out, cap);
}

// Round 8
// 883.215 us; speedup vs baseline: 1.4607x; 1.4607x over previous
//
#include <hip/hip_runtime.h>
#include <math.h>

constexpr int Bb = 4, Nn = 2048, Dd = 2048, Ee = 8, Cbn = 512;
constexpr int Mm = Bb * Nn;          // 8192 tokens

typedef _Float16 half8 __attribute__((ext_vector_type(8)));
typedef float floatx16 __attribute__((ext_vector_type(16)));

#define GLL16(g, l)                                                     \
  __builtin_amdgcn_global_load_lds(                                     \
      (const __attribute__((address_space(1))) void*)(g),               \
      (__attribute__((address_space(3))) void*)(l), 16, 0, 0)

// ---------------- transpose + split W: [E,D,C] f32 -> WT[hi/lo][E*C][D] -----
__global__ __launch_bounds__(256) void transpose_w(const float* __restrict__ W,
                                                   _Float16* __restrict__ WThi,
                                                   _Float16* __restrict__ WTlo) {
  const int kt = blockIdx.x;  // 0..31
  const int ct = blockIdx.y;  // 0..7
  const int e = blockIdx.z;   // 0..7
  __shared__ _Float16 thi[64][72];  // [c][k]
  __shared__ _Float16 tlo[64][72];
  const int tx = threadIdx.x & 15, ty = threadIdx.x >> 4;
  const float* src = W + ((size_t)(e * 2048 + kt * 64)) * 512 + ct * 64;
#pragma unroll
  for (int p = 0; p < 4; ++p) {
    int kk = ty + p * 16;
    float4 v = *(const float4*)(src + (size_t)kk * 512 + tx * 4);
    _Float16 h;
    h = (_Float16)v.x; thi[tx * 4 + 0][kk] = h; tlo[tx * 4 + 0][kk] = (_Float16)(v.x - (float)h);
    h = (_Float16)v.y; thi[tx * 4 + 1][kk] = h; tlo[tx * 4 + 1][kk] = (_Float16)(v.y - (float)h);
    h = (_Float16)v.z; thi[tx * 4 + 2][kk] = h; tlo[tx * 4 + 2][kk] = (_Float16)(v.z - (float)h);
    h = (_Float16)v.w; thi[tx * 4 + 3][kk] = h; tlo[tx * 4 + 3][kk] = (_Float16)(v.w - (float)h);
  }
  __syncthreads();
  const int rr = threadIdx.x >> 3;  // 0..31
  const int ch = threadIdx.x & 7;   // 16B chunk
  _Float16* dh = WThi + ((size_t)(e * 512 + ct * 64)) * 2048 + kt * 64;
  _Float16* dl = WTlo + ((size_t)(e * 512 + ct * 64)) * 2048 + kt * 64;
#pragma unroll
  for (int p = 0; p < 2; ++p) {
    int cc = rr + p * 32;
    *(half8*)(dh + (size_t)cc * 2048 + ch * 8) = *(const half8*)(&thi[cc][ch * 8]);
    *(half8*)(dl + (size_t)cc * 2048 + ch * 8) = *(const half8*)(&tlo[cc][ch * 8]);
  }
}

// ---------------- MFMA GEMM: BK=16, double-buffered LDS (2x16KB) ------------
// Per buffer: A fp32 128x64B (8KB) @0 | Bhi 128x32B (4KB) @8192 | Blo @12288.
// Issue kt+1's DMAs right after the barrier; compute kt overlaps their flight.
__global__ __launch_bounds__(256) void gemm_mfma(const float* __restrict__ X,
                                                 const _Float16* __restrict__ WThi,
                                                 const _Float16* __restrict__ WTlo,
                                                 float* __restrict__ partial) {
  const int bid = blockIdx.x;
  const int st = bid >> 8;
  const int stm = st & 3;
  const int stn = st >> 2;
  const int li = bid & 255;
  const int mtile = stm * 16 + (li >> 4);
  const int ntile = stn * 16 + (li & 15);

  const int tid = threadIdx.x;
  const int wave = tid >> 6, lane = tid & 63;
  const int wm = wave >> 1, wn = wave & 1;
  const int h = lane >> 5;

  __shared__ __align__(16) char lds[2][16384];

  // ---- A DMA mapping: wave w, q in {0,1}: rows w*32+q*16+(lane>>2),
  //      cpos=lane&3, global chunk cg = cpos ^ ((row>>1)&3), 16B chunks.
  const float* xgA[2];
  int ldsAoff[2];
#pragma unroll
  for (int q = 0; q < 2; ++q) {
    const int row = wave * 32 + q * 16 + (lane >> 2);
    const int cg = (lane & 3) ^ ((row >> 1) & 3);
    xgA[q] = X + (size_t)(mtile * 128 + row) * 2048 + cg * 4;
    ldsAoff[q] = wave * 2048 + q * 1024;  // wave-uniform; HW adds lane*16
  }
  // ---- B DMA mapping: row = w*32+(lane>>1), cpos=lane&1, cg = cpos^((row>>2)&1)
  const int rowBd = wave * 32 + (lane >> 1);
  const int cgB = (lane & 1) ^ ((rowBd >> 2) & 1);
  const _Float16* wgh = WThi + (size_t)(ntile * 128 + rowBd) * 2048 + cgB * 8;
  const _Float16* wgl = WTlo + (size_t)(ntile * 128 + rowBd) * 2048 + cgB * 8;
  const int ldsBoff = wave * 1024;  // within Bhi/Blo region

  // ---- A fragment read offsets: rows wm*64+(lane&31)(+32), chunks h*2+{0,1},
  //      pos = chunk ^ ((row>>1)&3); 2x b128 per row = 8 fp32 (K=16 slice h).
  const int rowA0 = wm * 64 + (lane & 31);
  const int rowA1 = rowA0 + 32;
  int oA0[2], oA1[2];
#pragma unroll
  for (int c = 0; c < 2; ++c) {
    oA0[c] = rowA0 * 64 + (((h * 2 + c) ^ ((rowA0 >> 1) & 3)) << 4);
    oA1[c] = rowA1 * 64 + (((h * 2 + c) ^ ((rowA1 >> 1) & 3)) << 4);
  }
  // ---- B fragment read offsets: rows wn*64+(lane&31)(+32), chunk h,
  //      pos = h ^ ((row>>2)&1)
  const int rowB0 = wn * 64 + (lane & 31);
  const int rowB1 = rowB0 + 32;
  const int oB0 = rowB0 * 32 + ((h ^ ((rowB0 >> 2) & 1)) << 4);
  const int oB1 = rowB1 * 32 + ((h ^ ((rowB1 >> 2) & 1)) << 4);

  floatx16 acc00 = {}, acc01 = {}, acc10 = {}, acc11 = {};

  auto issue = [&](int kt, int buf) {
    char* L = lds[buf];
    const int kA = kt * 16;  // fp32 elements
#pragma unroll
    for (int q = 0; q < 2; ++q) GLL16(xgA[q] + kA, L + ldsAoff[q]);
    GLL16(wgh + kA, L + 8192 + ldsBoff);
    GLL16(wgl + kA, L + 12288 + ldsBoff);
  };

  auto cvtA = [](const char* p0, const char* p1, half8& ah, half8& al) {
    float4 f0 = *(const float4*)p0;
    float4 f1 = *(const float4*)p1;
    float xf[8] = {f0.x, f0.y, f0.z, f0.w, f1.x, f1.y, f1.z, f1.w};
#pragma unroll
    for (int j = 0; j < 8; ++j) {
      _Float16 hv = (_Float16)xf[j];
      ah[j] = hv;
      al[j] = (_Float16)(xf[j] - (float)hv);
    }
  };

  issue(0, 0);
  int q = 0;
  for (int kt = 0; kt < 128; ++kt) {
    __syncthreads();  // drains DMAs -> buf q valid; prev compute done
    if (kt < 127) issue(kt + 1, q ^ 1);  // flies during compute below
    const char* A = lds[q];
    const char* Bhi = A + 8192;
    const char* Blo = A + 12288;
    half8 ah0, al0, ah1, al1;
    cvtA(A + oA0[0], A + oA0[1], ah0, al0);
    cvtA(A + oA1[0], A + oA1[1], ah1, al1);
    half8 bh0 = *(const half8*)(Bhi + oB0);
    half8 bh1 = *(const half8*)(Bhi + oB1);
    half8 bl0 = *(const half8*)(Blo + oB0);
    half8 bl1 = *(const half8*)(Blo + oB1);
    acc00 = __builtin_amdgcn_mfma_f32_32x32x16_f16(ah0, bh0, acc00, 0, 0, 0);
    acc00 = __builtin_amdgcn_mfma_f32_32x32x16_f16(ah0, bl0, acc00, 0, 0, 0);
    acc00 = __builtin_amdgcn_mfma_f32_32x32x16_f16(al0, bh0, acc00, 0, 0, 0);
    acc01 = __builtin_amdgcn_mfma_f32_32x32x16_f16(ah0, bh1, acc01, 0, 0, 0);
    acc01 = __builtin_amdgcn_mfma_f32_32x32x16_f16(ah0, bl1, acc01, 0, 0, 0);
    acc01 = __builtin_amdgcn_mfma_f32_32x32x16_f16(al0, bh1, acc01, 0, 0, 0);
    acc10 = __builtin_amdgcn_mfma_f32_32x32x16_f16(ah1, bh0, acc10, 0, 0, 0);
    acc10 = __builtin_amdgcn_mfma_f32_32x32x16_f16(ah1, bl0, acc10, 0, 0, 0);
    acc10 = __builtin_amdgcn_mfma_f32_32x32x16_f16(al1, bh0, acc10, 0, 0, 0);
    acc11 = __builtin_amdgcn_mfma_f32_32x32x16_f16(ah1, bh1, acc11, 0, 0, 0);
    acc11 = __builtin_amdgcn_mfma_f32_32x32x16_f16(ah1, bl1, acc11, 0, 0, 0);
    acc11 = __builtin_amdgcn_mfma_f32_32x32x16_f16(al1, bh1, acc11, 0, 0, 0);
    q ^= 1;
  }

  // epilogue: per-row sum of squares over this wave's 64 cols
  float myv = 0.f;
#pragma unroll
  for (int i = 0; i < 2; ++i) {
    const floatx16& c0 = i ? acc10 : acc00;
    const floatx16& c1 = i ? acc11 : acc01;
#pragma unroll
    for (int reg = 0; reg < 16; ++reg) {
      float v = c0[reg] * c0[reg] + c1[reg] * c1[reg];
#pragma unroll
      for (int m = 1; m <= 16; m <<= 1) v += __shfl_xor(v, m, 64);
      if ((lane & 31) == i * 16 + reg) myv = v;
    }
  }
  {
    const int i = (lane & 31) >> 4;
    const int reg = lane & 15;
    const int row = i * 32 + (reg & 3) + 8 * (reg >> 2) + 4 * h;
    const int token = mtile * 128 + wm * 64 + row;
    const int slice = ntile * 2 + wn;  // e*8+u
    partial[(size_t)token * 64 + slice] = myv;
  }
}

// ---------------- softmax + top-2 per token ---------------------------------
__global__ void route_kernel(const float* __restrict__ partial,
                             int* __restrict__ idx1, int* __restrict__ idx2,
                             float* __restrict__ p1, float* __restrict__ p2) {
  int t = blockIdx.x * blockDim.x + threadIdx.x;
  if (t >= Mm) return;
  float l[Ee];
  float mx = -1e30f;
#pragma unroll
  for (int e = 0; e < Ee; ++e) {
    float s = 0.f;
#pragma unroll
    for (int u = 0; u < 8; ++u) s += partial[(size_t)t * 64 + e * 8 + u];
    l[e] = sqrtf(s);
    mx = fmaxf(mx, l[e]);
  }
  float p[Ee];
  float s = 0.f;
#pragma unroll
  for (int e = 0; e < Ee; ++e) {
    p[e] = expf(l[e] - mx);
    s += p[e];
  }
  float inv = 1.f / s;
  int i1 = 0;
  float b1 = l[0];
#pragma unroll
  for (int e = 1; e < Ee; ++e)
    if (l[e] > b1) { b1 = l[e]; i1 = e; }
  int i2 = -1;
  float b2 = -1e30f;
#pragma unroll
  for (int e = 0; e < Ee; ++e)
    if (e != i1 && l[e] > b2) { b2 = l[e]; i2 = e; }
  idx1[t] = i1;
  idx2[t] = i2;
  p1[t] = p[i1] * inv;
  p2[t] = p[i2] * inv;
}

// ---------------- per-batch capacity priority scan --------------------------
__global__ void scan_kernel(const int* __restrict__ idx1,
                            const int* __restrict__ idx2,
                            int* __restrict__ prios) {
  const int b = blockIdx.x;
  const int tid = threadIdx.x;
  __shared__ int cnts[256][8];
  int cnt[8] = {0, 0, 0, 0, 0, 0, 0, 0};
  int eloc[16];
  const int base_p = tid * 16;
#pragma unroll
  for (int i = 0; i < 16; ++i) {
    int p = base_p + i;
    int k = p >> 11;
    int n = p & (Nn - 1);
    int e = (k == 0 ? idx1 : idx2)[b * Nn + n];
    eloc[i] = e;
    cnt[e]++;
  }
#pragma unroll
  for (int e = 0; e < 8; ++e) cnts[tid][e] = cnt[e];
  __syncthreads();
  if (tid < 8) {
    int run = 0;
    for (int i = 0; i < 256; ++i) {
      int v = cnts[i][tid];
      cnts[i][tid] = run;
      run += v;
    }
  }
  __syncthreads();
  int base[8];
#pragma unroll
  for (int e = 0; e < 8; ++e) base[e] = cnts[tid][e];
#pragma unroll
  for (int i = 0; i < 16; ++i) {
    int e = eloc[i];
    prios[b * 2 * Nn + base_p + i] = base[e]++;
  }
}

// ---------------- zero output ------------------------------------------------
__global__ void zero_kernel(float4* __restrict__ out, int n4) {
  int i = blockIdx.x * blockDim.x + threadIdx.x;
  if (i < n4) out[i] = make_float4(0.f, 0.f, 0.f, 0.f);
}

// ---------------- scatter dispatch/combine ----------------------------------
__global__ void scatter_kernel(const int* __restrict__ idx1,
                               const int* __restrict__ idx2,
                               const float* __restrict__ p1,
                               const float* __restrict__ p2,
                               const int* __restrict__ prios,
                               float* __restrict__ out, int cap) {
  int t = blockIdx.x * blockDim.x + threadIdx.x;
  if (t >= Mm) return;
  int b = t >> 11;
  int n = t & (Nn - 1);
  size_t disp = (size_t)t * Ee * cap;
  size_t comb = disp + (size_t)Mm * Ee * cap;
  {
    int e = idx1[t];
    int p = prios[b * 2 * Nn + n];
    if (p < cap) {
      out[disp + (size_t)e * cap + p] = 1.f;
      out[comb + (size_t)e * cap + p] = p1[t];
    }
  }
  {
    int e = idx2[t];
    int p = prios[b * 2 * Nn + Nn + n];
    if (p < cap) {
      out[disp + (size_t)e * cap + p] = 1.f;
      out[comb + (size_t)e * cap + p] = p2[t];
    }
  }
}

extern "C" void kernel_launch(void* const* d_in, const int* in_sizes, int n_in,
                              void* d_out, int out_size, void* d_ws, size_t ws_size,
                              hipStream_t stream) {
  const float* X = (const float*)d_in[0];
  const float* W = (const float*)d_in[1];
  float* out = (float*)d_out;
  const int cap = out_size / (2 * Bb * Nn * Ee);  // 640

  char* ws = (char*)d_ws;
  _Float16* WThi = (_Float16*)ws;                  // 16 MB
  _Float16* WTlo = (_Float16*)(ws + 16777216ull);  // 16 MB
  float* partial = (float*)(ws + 33554432ull);     // Mm*64 f32 = 2 MB
  int* idx1 = (int*)(ws + 35651584ull);
  int* idx2 = idx1 + Mm;
  float* p1 = (float*)(idx2 + Mm);
  float* p2 = p1 + Mm;
  int* prios = (int*)(p2 + Mm);

  transpose_w<<<dim3(32, 8, 8), 256, 0, stream>>>(W, WThi, WTlo);
  gemm_mfma<<<2048, 256, 0, stream>>>(X, WThi, WTlo, partial);
  route_kernel<<<Mm / 256, 256, 0, stream>>>(partial, idx1, idx2, p1, p2);
  scan_kernel<<<Bb, 256, 0, stream>>>(idx1, idx2, prios);
  const int n4 = out_size / 4;
  zero_kernel<<<(n4 + 255) / 256, 256, 0, stream>>>((float4*)out, n4);
  scatter_kernel<<<Mm / 256, 256, 0, stream>>>(idx1, idx2, p1, p2, prios, out, cap);
}

// Round 9
// 880.105 us; speedup vs baseline: 1.4658x; 1.0035x over previous
//
#include <hip/hip_runtime.h>
#include <math.h>

constexpr int Bb = 4, Nn = 2048, Dd = 2048, Ee = 8, Cbn = 512;
constexpr int Mm = Bb * Nn;          // 8192 tokens

typedef _Float16 half8 __attribute__((ext_vector_type(8)));
typedef float floatx16 __attribute__((ext_vector_type(16)));

#define GLL16(g, l)                                                     \
  __builtin_amdgcn_global_load_lds(                                     \
      (const __attribute__((address_space(1))) void*)(g),               \
      (__attribute__((address_space(3))) void*)(l), 16, 0, 0)

// ---------------- transpose + split W: [E,D,C] f32 -> WT[hi/lo][E*C][D] -----
__global__ __launch_bounds__(256) void transpose_w(const float* __restrict__ W,
                                                   _Float16* __restrict__ WThi,
                                                   _Float16* __restrict__ WTlo) {
  const int kt = blockIdx.x;  // 0..31
  const int ct = blockIdx.y;  // 0..7
  const int e = blockIdx.z;   // 0..7
  __shared__ _Float16 thi[64][72];  // [c][k]
  __shared__ _Float16 tlo[64][72];
  const int tx = threadIdx.x & 15, ty = threadIdx.x >> 4;
  const float* src = W + ((size_t)(e * 2048 + kt * 64)) * 512 + ct * 64;
#pragma unroll
  for (int p = 0; p < 4; ++p) {
    int kk = ty + p * 16;
    float4 v = *(const float4*)(src + (size_t)kk * 512 + tx * 4);
    _Float16 h;
    h = (_Float16)v.x; thi[tx * 4 + 0][kk] = h; tlo[tx * 4 + 0][kk] = (_Float16)(v.x - (float)h);
    h = (_Float16)v.y; thi[tx * 4 + 1][kk] = h; tlo[tx * 4 + 1][kk] = (_Float16)(v.y - (float)h);
    h = (_Float16)v.z; thi[tx * 4 + 2][kk] = h; tlo[tx * 4 + 2][kk] = (_Float16)(v.z - (float)h);
    h = (_Float16)v.w; thi[tx * 4 + 3][kk] = h; tlo[tx * 4 + 3][kk] = (_Float16)(v.w - (float)h);
  }
  __syncthreads();
  const int rr = threadIdx.x >> 3;  // 0..31
  const int ch = threadIdx.x & 7;   // 16B chunk
  _Float16* dh = WThi + ((size_t)(e * 512 + ct * 64)) * 2048 + kt * 64;
  _Float16* dl = WTlo + ((size_t)(e * 512 + ct * 64)) * 2048 + kt * 64;
#pragma unroll
  for (int p = 0; p < 2; ++p) {
    int cc = rr + p * 32;
    *(half8*)(dh + (size_t)cc * 2048 + ch * 8) = *(const half8*)(&thi[cc][ch * 8]);
    *(half8*)(dl + (size_t)cc * 2048 + ch * 8) = *(const half8*)(&tlo[cc][ch * 8]);
  }
}

// ---------------- MFMA GEMM: producer/consumer wave pipeline ----------------
// 6 waves: 0-3 consume (64x64 MFMA tiles), 4-5 produce (one 32KB buffer each,
// ping-pong on kt&1). No __syncthreads in the K-loop -> no full vmcnt drain;
// producers wait vmcnt(0) on their OWN loads only and signal via LDS flags.
__global__ __launch_bounds__(384, 3) void gemm_mfma(const float* __restrict__ X,
                                                    const _Float16* __restrict__ WThi,
                                                    const _Float16* __restrict__ WTlo,
                                                    float* __restrict__ partial) {
  const int bid = blockIdx.x;
  const int st = bid >> 8;
  const int stm = st & 3;
  const int stn = st >> 2;
  const int li = bid & 255;
  const int mtile = stm * 16 + (li >> 4);
  const int ntile = stn * 16 + (li & 15);

  const int tid = threadIdx.x;
  const int wave = tid >> 6, lane = tid & 63;

  // per buffer: A fp32 128x128B @0 (16KB) | Bhi 128x64B @16384 | Blo @24576
  __shared__ __align__(16) char smem[65536];
  __shared__ int flg[4];  // ready[0..1] (fill count), done[2..3] (use count*4)

  if (tid < 4) flg[tid] = 0;
  __syncthreads();  // only barrier in the kernel

  if (wave >= 4) {
    // ======================= producer =======================
    const int pb = wave - 4;            // my buffer
    const int lrA8 = lane >> 3;         // row within 8-row DMA group
    const int cgA = (lane & 7) ^ lrA8;  // XOR-swizzled global chunk (A)
    const float* aBase = X + (size_t)(mtile * 128 + lrA8) * 2048 + cgA * 4;
    const int lrB16 = lane >> 2;        // row within 16-row DMA group
    const int cgB = (lane & 3) ^ ((lane >> 3) & 3);
    const _Float16* bhBase = WThi + (size_t)(ntile * 128 + lrB16) * 2048 + cgB * 8;
    const _Float16* blBase = WTlo + (size_t)(ntile * 128 + lrB16) * 2048 + cgB * 8;
    char* L = smem + (pb << 15);
    for (int f = 0; f < 32; ++f) {
      if (f > 0) {
        while (__hip_atomic_load(&flg[2 + pb], __ATOMIC_ACQUIRE,
                                 __HIP_MEMORY_SCOPE_WORKGROUP) < 4 * f)
          __builtin_amdgcn_s_sleep(1);
      }
      const int k0 = (2 * f + pb) * 32;
#pragma unroll
      for (int i = 0; i < 16; ++i)
        GLL16(aBase + (size_t)(i * 8) * 2048 + k0, L + i * 1024);
#pragma unroll
      for (int i = 0; i < 8; ++i) {
        GLL16(bhBase + (size_t)(i * 16) * 2048 + k0, L + 16384 + i * 1024);
        GLL16(blBase + (size_t)(i * 16) * 2048 + k0, L + 24576 + i * 1024);
      }
      __builtin_amdgcn_s_waitcnt(0x0f70);  // vmcnt(0) only (exp=7, lgkm=15)
      __hip_atomic_store(&flg[pb], f + 1, __ATOMIC_RELEASE,
                         __HIP_MEMORY_SCOPE_WORKGROUP);
    }
    return;
  }

  // ======================= consumer =======================
  const int wm = wave >> 1, wn = wave & 1;
  const int h = lane >> 5;

  const int keyA = lane & 7;
  const int rowA0 = wm * 64 + (lane & 31);
  const int rowA1 = rowA0 + 32;
  int oAf0[2][2], oAf1[2][2];
#pragma unroll
  for (int s = 0; s < 2; ++s)
#pragma unroll
    for (int c = 0; c < 2; ++c) {
      const int g = s * 4 + h * 2 + c;
      oAf0[s][c] = rowA0 * 128 + ((g ^ keyA) << 4);
      oAf1[s][c] = rowA1 * 128 + ((g ^ keyA) << 4);
    }
  const int rB0 = wn * 64 + (lane & 31);
  const int rB1 = rB0 + 32;
  auto foffB = [&](int r, int s) {
    return r * 64 + (((s * 2 + h) ^ ((r >> 1) & 3)) << 4);
  };
  const int oB0[2] = {foffB(rB0, 0), foffB(rB0, 1)};
  const int oB1[2] = {foffB(rB1, 0), foffB(rB1, 1)};

  auto cvtA = [](const char* p0, const char* p1, half8& ah, half8& al) {
    float4 f0 = *(const float4*)p0;
    float4 f1 = *(const float4*)p1;
    float xf[8] = {f0.x, f0.y, f0.z, f0.w, f1.x, f1.y, f1.z, f1.w};
#pragma unroll
    for (int j = 0; j < 8; ++j) {
      _Float16 hv = (_Float16)xf[j];
      ah[j] = hv;
      al[j] = (_Float16)(xf[j] - (float)hv);
    }
  };

  floatx16 acc00 = {}, acc01 = {}, acc10 = {}, acc11 = {};

  for (int kt = 0; kt < 64; ++kt) {
    const int b = kt & 1;
    while (__hip_atomic_load(&flg[b], __ATOMIC_ACQUIRE,
                             __HIP_MEMORY_SCOPE_WORKGROUP) < (kt >> 1) + 1)
      __builtin_amdgcn_s_sleep(1);
    const char* A = smem + (b << 15);
    const char* Bhi = A + 16384;
    const char* Blo = A + 24576;
#pragma unroll
    for (int s = 0; s < 2; ++s) {
      half8 ah0, al0, ah1, al1;
      cvtA(A + oAf0[s][0], A + oAf0[s][1], ah0, al0);
      cvtA(A + oAf1[s][0], A + oAf1[s][1], ah1, al1);
      half8 bh0 = *(const half8*)(Bhi + oB0[s]);
      half8 bh1 = *(const half8*)(Bhi + oB1[s]);
      half8 bl0 = *(const half8*)(Blo + oB0[s]);
      half8 bl1 = *(const half8*)(Blo + oB1[s]);
      acc00 = __builtin_amdgcn_mfma_f32_32x32x16_f16(ah0, bh0, acc00, 0, 0, 0);
      acc00 = __builtin_amdgcn_mfma_f32_32x32x16_f16(ah0, bl0, acc00, 0, 0, 0);
      acc00 = __builtin_amdgcn_mfma_f32_32x32x16_f16(al0, bh0, acc00, 0, 0, 0);
      acc01 = __builtin_amdgcn_mfma_f32_32x32x16_f16(ah0, bh1, acc01, 0, 0, 0);
      acc01 = __builtin_amdgcn_mfma_f32_32x32x16_f16(ah0, bl1, acc01, 0, 0, 0);
      acc01 = __builtin_amdgcn_mfma_f32_32x32x16_f16(al0, bh1, acc01, 0, 0, 0);
      acc10 = __builtin_amdgcn_mfma_f32_32x32x16_f16(ah1, bh0, acc10, 0, 0, 0);
      acc10 = __builtin_amdgcn_mfma_f32_32x32x16_f16(ah1, bl0, acc10, 0, 0, 0);
      acc10 = __builtin_amdgcn_mfma_f32_32x32x16_f16(al1, bh0, acc10, 0, 0, 0);
      acc11 = __builtin_amdgcn_mfma_f32_32x32x16_f16(ah1, bh1, acc11, 0, 0, 0);
      acc11 = __builtin_amdgcn_mfma_f32_32x32x16_f16(ah1, bl1, acc11, 0, 0, 0);
      acc11 = __builtin_amdgcn_mfma_f32_32x32x16_f16(al1, bh1, acc11, 0, 0, 0);
    }
    // reads for buffer b have drained (release forces lgkmcnt wait) before
    // the producer is allowed to overwrite it
    if (lane == 0)
      __hip_atomic_fetch_add(&flg[2 + b], 1, __ATOMIC_RELEASE,
                             __HIP_MEMORY_SCOPE_WORKGROUP);
  }

  // epilogue: per-row sum of squares over this wave's 64 cols
  float myv = 0.f;
#pragma unroll
  for (int i = 0; i < 2; ++i) {
    const floatx16& c0 = i ? acc10 : acc00;
    const floatx16& c1 = i ? acc11 : acc01;
#pragma unroll
    for (int reg = 0; reg < 16; ++reg) {
      float v = c0[reg] * c0[reg] + c1[reg] * c1[reg];
#pragma unroll
      for (int m = 1; m <= 16; m <<= 1) v += __shfl_xor(v, m, 64);
      if ((lane & 31) == i * 16 + reg) myv = v;
    }
  }
  {
    const int i = (lane & 31) >> 4;
    const int reg = lane & 15;
    const int row = i * 32 + (reg & 3) + 8 * (reg >> 2) + 4 * h;
    const int token = mtile * 128 + wm * 64 + row;
    const int slice = ntile * 2 + wn;  // e*8+u
    partial[(size_t)token * 64 + slice] = myv;
  }
}

// ---------------- softmax + top-2 per token ---------------------------------
__global__ void route_kernel(const float* __restrict__ partial,
                             int* __restrict__ idx1, int* __restrict__ idx2,
                             float* __restrict__ p1, float* __restrict__ p2) {
  int t = blockIdx.x * blockDim.x + threadIdx.x;
  if (t >= Mm) return;
  float l[Ee];
  float mx = -1e30f;
#pragma unroll
  for (int e = 0; e < Ee; ++e) {
    float s = 0.f;
#pragma unroll
    for (int u = 0; u < 8; ++u) s += partial[(size_t)t * 64 + e * 8 + u];
    l[e] = sqrtf(s);
    mx = fmaxf(mx, l[e]);
  }
  float p[Ee];
  float s = 0.f;
#pragma unroll
  for (int e = 0; e < Ee; ++e) {
    p[e] = expf(l[e] - mx);
    s += p[e];
  }
  float inv = 1.f / s;
  int i1 = 0;
  float b1 = l[0];
#pragma unroll
  for (int e = 1; e < Ee; ++e)
    if (l[e] > b1) { b1 = l[e]; i1 = e; }
  int i2 = -1;
  float b2 = -1e30f;
#pragma unroll
  for (int e = 0; e < Ee; ++e)
    if (e != i1 && l[e] > b2) { b2 = l[e]; i2 = e; }
  idx1[t] = i1;
  idx2[t] = i2;
  p1[t] = p[i1] * inv;
  p2[t] = p[i2] * inv;
}

// ---------------- per-batch capacity priority scan --------------------------
__global__ void scan_kernel(const int* __restrict__ idx1,
                            const int* __restrict__ idx2,
                            int* __restrict__ prios) {
  const int b = blockIdx.x;
  const int tid = threadIdx.x;
  __shared__ int cnts[256][8];
  int cnt[8] = {0, 0, 0, 0, 0, 0, 0, 0};
  int eloc[16];
  const int base_p = tid * 16;
#pragma unroll
  for (int i = 0; i < 16; ++i) {
    int p = base_p + i;
    int k = p >> 11;
    int n = p & (Nn - 1);
    int e = (k == 0 ? idx1 : idx2)[b * Nn + n];
    eloc[i] = e;
    cnt[e]++;
  }
#pragma unroll
  for (int e = 0; e < 8; ++e) cnts[tid][e] = cnt[e];
  __syncthreads();
  if (tid < 8) {
    int run = 0;
    for (int i = 0; i < 256; ++i) {
      int v = cnts[i][tid];
      cnts[i][tid] = run;
      run += v;
    }
  }
  __syncthreads();
  int base[8];
#pragma unroll
  for (int e = 0; e < 8; ++e) base[e] = cnts[tid][e];
#pragma unroll
  for (int i = 0; i < 16; ++i) {
    int e = eloc[i];
    prios[b * 2 * Nn + base_p + i] = base[e]++;
  }
}

// ---------------- zero output ------------------------------------------------
__global__ void zero_kernel(float4* __restrict__ out, int n4) {
  int i = blockIdx.x * blockDim.x + threadIdx.x;
  if (i < n4) out[i] = make_float4(0.f, 0.f, 0.f, 0.f);
}

// ---------------- scatter dispatch/combine ----------------------------------
__global__ void scatter_kernel(const int* __restrict__ idx1,
                               const int* __restrict__ idx2,
                               const float* __restrict__ p1,
                               const float* __restrict__ p2,
                               const int* __restrict__ prios,
                               float* __restrict__ out, int cap) {
  int t = blockIdx.x * blockDim.x + threadIdx.x;
  if (t >= Mm) return;
  int b = t >> 11;
  int n = t & (Nn - 1);
  size_t disp = (size_t)t * Ee * cap;
  size_t comb = disp + (size_t)Mm * Ee * cap;
  {
    int e = idx1[t];
    int p = prios[b * 2 * Nn + n];
    if (p < cap) {
      out[disp + (size_t)e * cap + p] = 1.f;
      out[comb + (size_t)e * cap + p] = p1[t];
    }
  }
  {
    int e = idx2[t];
    int p = prios[b * 2 * Nn + Nn + n];
    if (p < cap) {
      out[disp + (size_t)e * cap + p] = 1.f;
      out[comb + (size_t)e * cap + p] = p2[t];
    }
  }
}

extern "C" void kernel_launch(void* const* d_in, const int* in_sizes, int n_in,
                              void* d_out, int out_size, void* d_ws, size_t ws_size,
                              hipStream_t stream) {
  const float* X = (const float*)d_in[0];
  const float* W = (const float*)d_in[1];
  float* out = (float*)d_out;
  const int cap = out_size / (2 * Bb * Nn * Ee);  // 640

  char* ws = (char*)d_ws;
  _Float16* WThi = (_Float16*)ws;                  // 16 MB
  _Float16* WTlo = (_Float16*)(ws + 16777216ull);  // 16 MB
  float* partial = (float*)(ws + 33554432ull);     // Mm*64 f32 = 2 MB
  int* idx1 = (int*)(ws + 35651584ull);
  int* idx2 = idx1 + Mm;
  float* p1 = (float*)(idx2 + Mm);
  float* p2 = p1 + Mm;
  int* prios = (int*)(p2 + Mm);

  transpose_w<<<dim3(32, 8, 8), 256, 0, stream>>>(W, WThi, WTlo);
  gemm_mfma<<<2048, 384, 0, stream>>>(X, WThi, WTlo, partial);
  route_kernel<<<Mm / 256, 256, 0, stream>>>(partial, idx1, idx2, p1, p2);
  scan_kernel<<<Bb, 256, 0, stream>>>(idx1, idx2, prios);
  const int n4 = out_size / 4;
  zero_kernel<<<(n4 + 255) / 256, 256, 0, stream>>>((float4*)out, n4);
  scatter_kernel<<<Mm / 256, 256, 0, stream>>>(idx1, idx2, p1, p2, prios, out, cap);
}